// Round 1
// baseline (808.745 us; speedup 1.0000x reference)
//
#include <hip/hip_runtime.h>
#include <math.h>

// Problem constants (from reference setup_inputs)
#define BB 16
#define CC 192
#define KK 3
#define HH 48
#define WW 48
#define HW (HH * WW)                 // 2304
#define N_Y (BB * CC * HW)           // 7,077,888
#define IMG 768
#define N_X (BB * 3 * IMG * IMG)     // 28,311,552
#define N_Z (BB * CC * 12 * 12)      // 442,368
#define NUM_PIXELS (BB * IMG * IMG)  // 9,437,184

#define INV_LN2 1.4426950408889634f
#define NEG_INV_SQRT2 -0.7071067811865476f

__device__ __forceinline__ float std_cdf(float t) {
    return 0.5f * erfcf(NEG_INV_SQRT2 * t);
}

// Block (256 threads) reduction -> single double atomicAdd
__device__ __forceinline__ void block_atomic_add(double* dst, float val) {
    #pragma unroll
    for (int off = 32; off > 0; off >>= 1)
        val += __shfl_down(val, off, 64);
    __shared__ float smem[4];
    int lane = threadIdx.x & 63;
    int wid  = threadIdx.x >> 6;
    if (lane == 0) smem[wid] = val;
    __syncthreads();
    if (threadIdx.x == 0) {
        float s = smem[0] + smem[1] + smem[2] + smem[3];
        atomicAdd(dst, (double)s);
    }
}

// ---------------- Kernel 1: MSE partial sums (vectorized float4) -------------
__global__ void mse_kernel(const float* __restrict__ x,
                           const float* __restrict__ xh,
                           double* __restrict__ acc) {
    const int n4 = N_X / 4;
    float s = 0.0f;
    const float4* x4  = (const float4*)x;
    const float4* xh4 = (const float4*)xh;
    for (int i = blockIdx.x * blockDim.x + threadIdx.x; i < n4;
         i += gridDim.x * blockDim.x) {
        float4 a = x4[i];
        float4 b = xh4[i];
        float d0 = b.x - a.x, d1 = b.y - a.y, d2 = b.z - a.z, d3 = b.w - a.w;
        s += d0 * d0 + d1 * d1 + d2 * d2 + d3 * d3;
    }
    block_atomic_add(acc, s);
}

// ---------------- Kernel 2: GMM latent rate ---------------------------------
// One thread per (b,c,h,w) element.
__global__ void gmm_kernel(const float* __restrict__ params,
                           const float* __restrict__ y_hat,
                           double* __restrict__ acc) {
    int idx = blockIdx.x * blockDim.x + threadIdx.x;   // exact grid: N_Y
    float y = y_hat[idx];

    // params layout (B, C, 3, K, H, W): base = (idx/HW)*9*HW + idx%HW
    int bc = idx / HW;
    int hw = idx - bc * HW;
    const float* p = params + (size_t)bc * (9 * HW) + hw;

    // slice s = i*K + k, at offset s*HW
    float w0 = p[0 * HW], w1 = p[1 * HW], w2 = p[2 * HW];   // logits
    float m0 = p[3 * HW], m1 = p[4 * HW], m2 = p[5 * HW];   // means
    float s0 = p[6 * HW], s1 = p[7 * HW], s2 = p[8 * HW];   // log-scales

    // log_softmax over logits
    float mw = fmaxf(w0, fmaxf(w1, w2));
    float lse = mw + logf(__expf(w0 - mw) + __expf(w1 - mw) + __expf(w2 - mw));
    float lw0 = w0 - lse, lw1 = w1 - lse, lw2 = w2 - lse;

    float sc0 = fmaxf(expf(s0), 1e-5f);
    float sc1 = fmaxf(expf(s1), 1e-5f);
    float sc2 = fmaxf(expf(s2), 1e-5f);

    float pmf0 = fmaxf(std_cdf((y + 0.5f - m0) / sc0) - std_cdf((y - 0.5f - m0) / sc0), 1e-6f);
    float pmf1 = fmaxf(std_cdf((y + 0.5f - m1) / sc1) - std_cdf((y - 0.5f - m1) / sc1), 1e-6f);
    float pmf2 = fmaxf(std_cdf((y + 0.5f - m2) / sc2) - std_cdf((y - 0.5f - m2) / sc2), 1e-6f);

    float t0 = lw0 + logf(pmf0);
    float t1 = lw1 + logf(pmf1);
    float t2 = lw2 + logf(pmf2);

    float mt = fmaxf(t0, fmaxf(t1, t2));
    float lpt = mt + logf(__expf(t0 - mt) + __expf(t1 - mt) + __expf(t2 - mt));

    float rate = -lpt * INV_LN2;
    block_atomic_add(acc, rate);
}

// ---------------- Kernel 3: hyperlatent rate --------------------------------
__global__ void hyper_kernel(const float* __restrict__ z,
                             double* __restrict__ acc) {
    int idx = blockIdx.x * blockDim.x + threadIdx.x;   // exact grid: N_Z
    float v = z[idx];
    float pmf = fmaxf(std_cdf(v + 0.5f) - std_cdf(v - 0.5f), 1e-6f);
    float rate = -log2f(pmf);
    block_atomic_add(acc, rate);
}

// ---------------- Kernel 4: finalize ----------------------------------------
__global__ void finalize_kernel(const double* __restrict__ acc,
                                float* __restrict__ out) {
    double distortion = acc[0] / (double)N_X;
    double rate_y = acc[1] / (double)BB;   // mean over batch of per-batch sums
    double rate_z = acc[2] / (double)BB;
    double bpp = (rate_y + rate_z) / (double)NUM_PIXELS;
    double loss = 0.01 * 255.0 * 255.0 * distortion + bpp;
    out[0] = (float)loss;
    out[1] = (float)distortion;
    out[2] = (float)bpp;
}

extern "C" void kernel_launch(void* const* d_in, const int* in_sizes, int n_in,
                              void* d_out, int out_size, void* d_ws, size_t ws_size,
                              hipStream_t stream) {
    const float* x      = (const float*)d_in[0];
    const float* x_hat  = (const float*)d_in[1];
    const float* params = (const float*)d_in[2];
    const float* y_hat  = (const float*)d_in[3];
    const float* z_hat  = (const float*)d_in[4];
    float* out = (float*)d_out;
    double* acc = (double*)d_ws;   // acc[0]=sq_diff, acc[1]=rate_y, acc[2]=rate_z

    hipMemsetAsync(d_ws, 0, 3 * sizeof(double), stream);

    mse_kernel<<<4096, 256, 0, stream>>>(x, x_hat, &acc[0]);
    gmm_kernel<<<N_Y / 256, 256, 0, stream>>>(params, y_hat, &acc[1]);
    hyper_kernel<<<N_Z / 256, 256, 0, stream>>>(z_hat, &acc[2]);
    finalize_kernel<<<1, 1, 0, stream>>>(acc, out);
}

// Round 2
// 517.499 us; speedup vs baseline: 1.5628x; 1.5628x over previous
//
#include <hip/hip_runtime.h>
#include <math.h>

// Problem constants (from reference setup_inputs)
#define BB 16
#define CC 192
#define KK 3
#define HH 48
#define WW 48
#define HW (HH * WW)                 // 2304
#define N_Y (BB * CC * HW)           // 7,077,888
#define IMG 768
#define N_X (BB * 3 * IMG * IMG)     // 28,311,552
#define N_Z (BB * CC * 12 * 12)     // 442,368
#define NUM_PIXELS (BB * IMG * IMG)  // 9,437,184

#define INV_SQRT2 0.7071067811865476f

// Fused grid partition (4 elements/thread, 256 threads/block)
#define G_GMM   (N_Y / (256 * 4))    // 6912
#define G_MSE   2048                 // grid-stride
#define G_HYP   (N_Z / (256 * 4))    // 432
#define G_TOTAL (G_GMM + G_MSE + G_HYP)   // 9392
#define SWIZZLE_PRIME 7919           // coprime with 9392 -> bijective interleave

// Branch-free Abramowitz & Stegun 7.1.26 erf, |abs err| <= 1.5e-7.
// 1 rcp + 1 exp on the trans pipe, ~9 VALU ops.
__device__ __forceinline__ float erf_fast(float x) {
    float ax = fabsf(x);
    float t  = __builtin_amdgcn_rcpf(fmaf(0.3275911f, ax, 1.0f));
    float p  = t * fmaf(t, fmaf(t, fmaf(t, fmaf(t, 1.061405429f,
                 -1.453152027f), 1.421413741f), -0.284496736f), 0.254829592f);
    float e  = __expf(-ax * ax);
    float r  = fmaf(-p, e, 1.0f);          // erf(|x|)
    return copysignf(r, x);
}

// Block (256 threads) reduction -> single double atomicAdd
__device__ __forceinline__ void block_atomic_add(double* dst, float val) {
    #pragma unroll
    for (int off = 32; off > 0; off >>= 1)
        val += __shfl_down(val, off, 64);
    __shared__ float smem[4];
    int lane = threadIdx.x & 63;
    int wid  = threadIdx.x >> 6;
    if (lane == 0) smem[wid] = val;
    __syncthreads();
    if (threadIdx.x == 0) {
        float s = smem[0] + smem[1] + smem[2] + smem[3];
        atomicAdd(dst, (double)s);
    }
}

// GMM rate for one element. S/P trick:
//   logsumexp_k( logsoftmax(w)_k + log(pmf_k) ) = log(P*0.5/S)
//   with S = sum e^(w-mw),  P = sum e^(w-mw) * max(erf(xu)-erf(xl), 2e-6)
//   rate_bits = log2(S) - log2(P) + 1
__device__ __forceinline__ float gmm_rate(float y,
                                          float w0, float w1, float w2,
                                          float m0, float m1, float m2,
                                          float s0, float s1, float s2) {
    float mw = fmaxf(w0, fmaxf(w1, w2));
    float e0 = __expf(w0 - mw), e1 = __expf(w1 - mw), e2 = __expf(w2 - mw);
    float S = e0 + e1 + e2;

    // inv scale folded with 1/sqrt(2); matches clip(exp(s),1e-5) then divide
    float i0 = fminf(__expf(-s0), 1e5f) * INV_SQRT2;
    float i1 = fminf(__expf(-s1), 1e5f) * INV_SQRT2;
    float i2 = fminf(__expf(-s2), 1e5f) * INV_SQRT2;

    float yu = y + 0.5f, yl = y - 0.5f;

    float d0 = erf_fast((yu - m0) * i0) - erf_fast((yl - m0) * i0);
    float d1 = erf_fast((yu - m1) * i1) - erf_fast((yl - m1) * i1);
    float d2 = erf_fast((yu - m2) * i2) - erf_fast((yl - m2) * i2);

    float P = e0 * fmaxf(d0, 2e-6f);
    P = fmaf(e1, fmaxf(d1, 2e-6f), P);
    P = fmaf(e2, fmaxf(d2, 2e-6f), P);

    return __log2f(S) - __log2f(P) + 1.0f;
}

__global__ void __launch_bounds__(256)
fused_kernel(const float* __restrict__ x, const float* __restrict__ xh,
             const float* __restrict__ params, const float* __restrict__ y_hat,
             const float* __restrict__ z_hat, double* __restrict__ acc) {
    // Interleave work types across dispatch order so trans-bound GMM waves
    // and HBM-bound MSE waves co-resident on every CU from t=0.
    unsigned v = ((unsigned)blockIdx.x * SWIZZLE_PRIME) % G_TOTAL;

    if (v < G_GMM) {
        // ---- GMM latent rate: 4 consecutive hw elements per thread --------
        int gid = v * 256 + threadIdx.x;          // float4 index in [0, N_Y/4)
        int bc  = gid / (HW / 4);                 // which (b,c) plane group
        int hw4 = gid - bc * (HW / 4);
        const float4* p4 = (const float4*)params + (size_t)bc * (9 * HW / 4) + hw4;
        float4 y4 = ((const float4*)y_hat)[gid];

        float4 w0 = p4[0 * (HW/4)], w1 = p4[1 * (HW/4)], w2 = p4[2 * (HW/4)];
        float4 m0 = p4[3 * (HW/4)], m1 = p4[4 * (HW/4)], m2 = p4[5 * (HW/4)];
        float4 s0 = p4[6 * (HW/4)], s1 = p4[7 * (HW/4)], s2 = p4[8 * (HW/4)];

        float r = 0.0f;
        r += gmm_rate(y4.x, w0.x, w1.x, w2.x, m0.x, m1.x, m2.x, s0.x, s1.x, s2.x);
        r += gmm_rate(y4.y, w0.y, w1.y, w2.y, m0.y, m1.y, m2.y, s0.y, s1.y, s2.y);
        r += gmm_rate(y4.z, w0.z, w1.z, w2.z, m0.z, m1.z, m2.z, s0.z, s1.z, s2.z);
        r += gmm_rate(y4.w, w0.w, w1.w, w2.w, m0.w, m1.w, m2.w, s0.w, s1.w, s2.w);
        block_atomic_add(&acc[1], r);
    } else if (v < G_GMM + G_MSE) {
        // ---- MSE: grid-stride over float4 ---------------------------------
        int mb = v - G_GMM;
        const int n4 = N_X / 4;
        const float4* x4  = (const float4*)x;
        const float4* xh4 = (const float4*)xh;
        float s = 0.0f;
        for (int i = mb * 256 + threadIdx.x; i < n4; i += G_MSE * 256) {
            float4 a = x4[i];
            float4 b = xh4[i];
            float d0 = b.x - a.x, d1 = b.y - a.y, d2 = b.z - a.z, d3 = b.w - a.w;
            s += d0 * d0 + d1 * d1 + d2 * d2 + d3 * d3;
        }
        block_atomic_add(&acc[0], s);
    } else {
        // ---- Hyperlatent rate: 4 elements per thread ----------------------
        int hb  = v - G_GMM - G_MSE;
        int gid = hb * 256 + threadIdx.x;         // float4 index in [0, N_Z/4)
        float4 z4 = ((const float4*)z_hat)[gid];
        float r = 0.0f;
        #pragma unroll
        for (int j = 0; j < 4; ++j) {
            float z = (j == 0) ? z4.x : (j == 1) ? z4.y : (j == 2) ? z4.z : z4.w;
            float d = erf_fast((z + 0.5f) * INV_SQRT2)
                    - erf_fast((z - 0.5f) * INV_SQRT2);
            r += 1.0f - __log2f(fmaxf(d, 2e-6f));   // -log2(0.5*d clipped 1e-6)
        }
        block_atomic_add(&acc[2], r);
    }
}

__global__ void finalize_kernel(const double* __restrict__ acc,
                                float* __restrict__ out) {
    double distortion = acc[0] / (double)N_X;
    double rate_y = acc[1] / (double)BB;   // mean over batch of per-batch sums
    double rate_z = acc[2] / (double)BB;
    double bpp = (rate_y + rate_z) / (double)NUM_PIXELS;
    double loss = 0.01 * 255.0 * 255.0 * distortion + bpp;
    out[0] = (float)loss;
    out[1] = (float)distortion;
    out[2] = (float)bpp;
}

extern "C" void kernel_launch(void* const* d_in, const int* in_sizes, int n_in,
                              void* d_out, int out_size, void* d_ws, size_t ws_size,
                              hipStream_t stream) {
    const float* x      = (const float*)d_in[0];
    const float* x_hat  = (const float*)d_in[1];
    const float* params = (const float*)d_in[2];
    const float* y_hat  = (const float*)d_in[3];
    const float* z_hat  = (const float*)d_in[4];
    float* out = (float*)d_out;
    double* acc = (double*)d_ws;   // acc[0]=sq_diff, acc[1]=rate_y, acc[2]=rate_z

    hipMemsetAsync(d_ws, 0, 3 * sizeof(double), stream);
    fused_kernel<<<G_TOTAL, 256, 0, stream>>>(x, x_hat, params, y_hat, z_hat, acc);
    finalize_kernel<<<1, 1, 0, stream>>>(acc, out);
}

// Round 3
// 505.045 us; speedup vs baseline: 1.6013x; 1.0247x over previous
//
#include <hip/hip_runtime.h>
#include <math.h>

// Problem constants (from reference setup_inputs)
#define BB 16
#define CC 192
#define KK 3
#define HH 48
#define WW 48
#define HW (HH * WW)                 // 2304
#define N_Y (BB * CC * HW)           // 7,077,888
#define IMG 768
#define N_X (BB * 3 * IMG * IMG)     // 28,311,552
#define N_Z (BB * CC * 12 * 12)      // 442,368
#define NUM_PIXELS (BB * IMG * IMG)  // 9,437,184

#define INV_SQRT2 0.7071067811865476f

// Fused grid partition (4 elements/thread, 256 threads/block)
#define G_GMM   (N_Y / (256 * 4))    // 6912
#define G_MSE   2048                 // grid-stride
#define G_HYP   (N_Z / (256 * 4))    // 432
#define G_TOTAL (G_GMM + G_MSE + G_HYP)   // 9392
#define SWIZZLE_PRIME 7919           // coprime with 9392 -> bijective interleave

// Branch-free Abramowitz & Stegun 7.1.26 erf, |abs err| <= 1.5e-7.
__device__ __forceinline__ float erf_fast(float x) {
    float ax = fabsf(x);
    float t  = __builtin_amdgcn_rcpf(fmaf(0.3275911f, ax, 1.0f));
    float p  = t * fmaf(t, fmaf(t, fmaf(t, fmaf(t, 1.061405429f,
                 -1.453152027f), 1.421413741f), -0.284496736f), 0.254829592f);
    float e  = __expf(-ax * ax);
    float r  = fmaf(-p, e, 1.0f);          // erf(|x|)
    return copysignf(r, x);
}

// Block (256 threads) reduction; thread 0 writes partial to slot (no atomics —
// 9392 same-line device atomics serialized at ~18ns each = the R2 bottleneck).
__device__ __forceinline__ void block_write_partial(double* __restrict__ slot,
                                                    float val) {
    #pragma unroll
    for (int off = 32; off > 0; off >>= 1)
        val += __shfl_down(val, off, 64);
    __shared__ float smem[4];
    int lane = threadIdx.x & 63;
    int wid  = threadIdx.x >> 6;
    if (lane == 0) smem[wid] = val;
    __syncthreads();
    if (threadIdx.x == 0) {
        float s = smem[0] + smem[1] + smem[2] + smem[3];
        *slot = (double)s;
    }
}

// GMM rate:  logsumexp_k( logsoftmax(w)_k + log(pmf_k) ) collapsed to
//   rate_bits = log2(S) - log2(P) + 1,
//   S = sum e^(w-mw),  P = sum e^(w-mw) * max(erf(xu)-erf(xl), 2e-6)
__device__ __forceinline__ float gmm_rate(float y,
                                          float w0, float w1, float w2,
                                          float m0, float m1, float m2,
                                          float s0, float s1, float s2) {
    float mw = fmaxf(w0, fmaxf(w1, w2));
    float e0 = __expf(w0 - mw), e1 = __expf(w1 - mw), e2 = __expf(w2 - mw);
    float S = e0 + e1 + e2;

    float i0 = fminf(__expf(-s0), 1e5f) * INV_SQRT2;
    float i1 = fminf(__expf(-s1), 1e5f) * INV_SQRT2;
    float i2 = fminf(__expf(-s2), 1e5f) * INV_SQRT2;

    float yu = y + 0.5f, yl = y - 0.5f;

    float d0 = erf_fast((yu - m0) * i0) - erf_fast((yl - m0) * i0);
    float d1 = erf_fast((yu - m1) * i1) - erf_fast((yl - m1) * i1);
    float d2 = erf_fast((yu - m2) * i2) - erf_fast((yl - m2) * i2);

    float P = e0 * fmaxf(d0, 2e-6f);
    P = fmaf(e1, fmaxf(d1, 2e-6f), P);
    P = fmaf(e2, fmaxf(d2, 2e-6f), P);

    return __log2f(S) - __log2f(P) + 1.0f;
}

__global__ void __launch_bounds__(256)
fused_kernel(const float* __restrict__ x, const float* __restrict__ xh,
             const float* __restrict__ params, const float* __restrict__ y_hat,
             const float* __restrict__ z_hat, double* __restrict__ partial) {
    // Interleave work types so trans-bound GMM waves and HBM-bound MSE waves
    // are co-resident on every CU from t=0. v is a bijection of blockIdx.x,
    // so partial[v] slots partition into 3 contiguous segments by work type.
    unsigned v = ((unsigned)blockIdx.x * SWIZZLE_PRIME) % G_TOTAL;

    if (v < G_GMM) {
        // ---- GMM latent rate: 4 consecutive hw elements per thread --------
        int gid = v * 256 + threadIdx.x;          // float4 index in [0, N_Y/4)
        int bc  = gid / (HW / 4);
        int hw4 = gid - bc * (HW / 4);
        const float4* p4 = (const float4*)params + (size_t)bc * (9 * HW / 4) + hw4;
        float4 y4 = ((const float4*)y_hat)[gid];

        float4 w0 = p4[0 * (HW/4)], w1 = p4[1 * (HW/4)], w2 = p4[2 * (HW/4)];
        float4 m0 = p4[3 * (HW/4)], m1 = p4[4 * (HW/4)], m2 = p4[5 * (HW/4)];
        float4 s0 = p4[6 * (HW/4)], s1 = p4[7 * (HW/4)], s2 = p4[8 * (HW/4)];

        float r = 0.0f;
        r += gmm_rate(y4.x, w0.x, w1.x, w2.x, m0.x, m1.x, m2.x, s0.x, s1.x, s2.x);
        r += gmm_rate(y4.y, w0.y, w1.y, w2.y, m0.y, m1.y, m2.y, s0.y, s1.y, s2.y);
        r += gmm_rate(y4.z, w0.z, w1.z, w2.z, m0.z, m1.z, m2.z, s0.z, s1.z, s2.z);
        r += gmm_rate(y4.w, w0.w, w1.w, w2.w, m0.w, m1.w, m2.w, s0.w, s1.w, s2.w);
        block_write_partial(&partial[v], r);
    } else if (v < G_GMM + G_MSE) {
        // ---- MSE: grid-stride over float4 ---------------------------------
        int mb = v - G_GMM;
        const int n4 = N_X / 4;
        const float4* x4  = (const float4*)x;
        const float4* xh4 = (const float4*)xh;
        float s = 0.0f;
        for (int i = mb * 256 + threadIdx.x; i < n4; i += G_MSE * 256) {
            float4 a = x4[i];
            float4 b = xh4[i];
            float d0 = b.x - a.x, d1 = b.y - a.y, d2 = b.z - a.z, d3 = b.w - a.w;
            s += d0 * d0 + d1 * d1 + d2 * d2 + d3 * d3;
        }
        block_write_partial(&partial[v], s);
    } else {
        // ---- Hyperlatent rate: 4 elements per thread ----------------------
        int hb  = v - G_GMM - G_MSE;
        int gid = hb * 256 + threadIdx.x;         // float4 index in [0, N_Z/4)
        float4 z4 = ((const float4*)z_hat)[gid];
        float r = 0.0f;
        #pragma unroll
        for (int j = 0; j < 4; ++j) {
            float z = (j == 0) ? z4.x : (j == 1) ? z4.y : (j == 2) ? z4.z : z4.w;
            float d = erf_fast((z + 0.5f) * INV_SQRT2)
                    - erf_fast((z - 0.5f) * INV_SQRT2);
            r += 1.0f - __log2f(fmaxf(d, 2e-6f));
        }
        block_write_partial(&partial[v], r);
    }
}

// Reduce the 3 partial segments: [0,G_GMM)=rate_y, [G_GMM,+G_MSE)=sq_err,
// [G_GMM+G_MSE,G_TOTAL)=rate_z.  One block, 256 threads, double precision.
__global__ void __launch_bounds__(256)
finalize_kernel(const double* __restrict__ partial, float* __restrict__ out) {
    __shared__ double sm[256];
    double seg[3];
    const int lo[3] = {0, G_GMM, G_GMM + G_MSE};
    const int hi[3] = {G_GMM, G_GMM + G_MSE, G_TOTAL};
    for (int k = 0; k < 3; ++k) {
        double a = 0.0;
        for (int i = lo[k] + threadIdx.x; i < hi[k]; i += 256) a += partial[i];
        sm[threadIdx.x] = a;
        __syncthreads();
        for (int off = 128; off > 0; off >>= 1) {
            if (threadIdx.x < (unsigned)off) sm[threadIdx.x] += sm[threadIdx.x + off];
            __syncthreads();
        }
        seg[k] = sm[0];
        __syncthreads();
    }
    if (threadIdx.x == 0) {
        double rate_y     = seg[0];
        double sq_err     = seg[1];
        double rate_z     = seg[2];
        double distortion = sq_err / (double)N_X;
        double bpp = (rate_y / (double)BB + rate_z / (double)BB) / (double)NUM_PIXELS;
        double loss = 0.01 * 255.0 * 255.0 * distortion + bpp;
        out[0] = (float)loss;
        out[1] = (float)distortion;
        out[2] = (float)bpp;
    }
}

extern "C" void kernel_launch(void* const* d_in, const int* in_sizes, int n_in,
                              void* d_out, int out_size, void* d_ws, size_t ws_size,
                              hipStream_t stream) {
    const float* x      = (const float*)d_in[0];
    const float* x_hat  = (const float*)d_in[1];
    const float* params = (const float*)d_in[2];
    const float* y_hat  = (const float*)d_in[3];
    const float* z_hat  = (const float*)d_in[4];
    float* out = (float*)d_out;
    double* partial = (double*)d_ws;   // G_TOTAL doubles, all written each call

    fused_kernel<<<G_TOTAL, 256, 0, stream>>>(x, x_hat, params, y_hat, z_hat, partial);
    finalize_kernel<<<1, 256, 0, stream>>>(partial, out);
}

// Round 4
// 498.854 us; speedup vs baseline: 1.6212x; 1.0124x over previous
//
#include <hip/hip_runtime.h>
#include <math.h>

// Problem constants (from reference setup_inputs)
#define BB 16
#define CC 192
#define KK 3
#define HH 48
#define WW 48
#define HW (HH * WW)                 // 2304
#define N_Y (BB * CC * HW)           // 7,077,888
#define IMG 768
#define N_X (BB * 3 * IMG * IMG)     // 28,311,552
#define N_Z (BB * CC * 12 * 12)      // 442,368
#define NUM_PIXELS (BB * IMG * IMG)  // 9,437,184

#define INV_SQRT2 0.7071067811865476f

// Fused grid partition (8 elements/thread, 256 threads/block)
#define G_GMM   (N_Y / (256 * 8))    // 3456
#define G_MSE   1728                 // 4096 float4 per block, exact cover
#define G_HYP   (N_Z / (256 * 8))    // 216
#define G_TOTAL (G_GMM + G_MSE + G_HYP)   // 5400
#define SWIZZLE_PRIME 7919           // coprime with 5400 -> bijective interleave

typedef float v4f __attribute__((ext_vector_type(4)));

// Branch-free Abramowitz & Stegun 7.1.26 erf, |abs err| <= 1.5e-7.
__device__ __forceinline__ float erf_fast(float x) {
    float ax = fabsf(x);
    float t  = __builtin_amdgcn_rcpf(fmaf(0.3275911f, ax, 1.0f));
    float p  = t * fmaf(t, fmaf(t, fmaf(t, fmaf(t, 1.061405429f,
                 -1.453152027f), 1.421413741f), -0.284496736f), 0.254829592f);
    float e  = __expf(-ax * ax);
    float r  = fmaf(-p, e, 1.0f);          // erf(|x|)
    return copysignf(r, x);
}

// Block (256 threads) reduction; thread 0 writes partial to slot.
__device__ __forceinline__ void block_write_partial(double* __restrict__ slot,
                                                    float val) {
    #pragma unroll
    for (int off = 32; off > 0; off >>= 1)
        val += __shfl_down(val, off, 64);
    __shared__ float smem[4];
    int lane = threadIdx.x & 63;
    int wid  = threadIdx.x >> 6;
    if (lane == 0) smem[wid] = val;
    __syncthreads();
    if (threadIdx.x == 0) {
        float s = smem[0] + smem[1] + smem[2] + smem[3];
        *slot = (double)s;
    }
}

// GMM rate:  logsumexp_k( logsoftmax(w)_k + log(pmf_k) ) collapsed to
//   rate_bits = log2(S) - log2(P) + 1,
//   S = sum e^(w-mw),  P = sum e^(w-mw) * max(erf(xu)-erf(xl), 2e-6)
__device__ __forceinline__ float gmm_rate(float y,
                                          float w0, float w1, float w2,
                                          float m0, float m1, float m2,
                                          float s0, float s1, float s2) {
    float mw = fmaxf(w0, fmaxf(w1, w2));
    float e0 = __expf(w0 - mw), e1 = __expf(w1 - mw), e2 = __expf(w2 - mw);
    float S = e0 + e1 + e2;

    float i0 = fminf(__expf(-s0), 1e5f) * INV_SQRT2;
    float i1 = fminf(__expf(-s1), 1e5f) * INV_SQRT2;
    float i2 = fminf(__expf(-s2), 1e5f) * INV_SQRT2;

    float yu = y + 0.5f, yl = y - 0.5f;

    float d0 = erf_fast((yu - m0) * i0) - erf_fast((yl - m0) * i0);
    float d1 = erf_fast((yu - m1) * i1) - erf_fast((yl - m1) * i1);
    float d2 = erf_fast((yu - m2) * i2) - erf_fast((yl - m2) * i2);

    float P = e0 * fmaxf(d0, 2e-6f);
    P = fmaf(e1, fmaxf(d1, 2e-6f), P);
    P = fmaf(e2, fmaxf(d2, 2e-6f), P);

    return __log2f(S) - __log2f(P) + 1.0f;
}

__global__ void __launch_bounds__(256)
fused_kernel(const float* __restrict__ x, const float* __restrict__ xh,
             const float* __restrict__ params, const float* __restrict__ y_hat,
             const float* __restrict__ z_hat, double* __restrict__ partial) {
    // Bijective swizzle interleaves work types across dispatch order; slots in
    // partial[] remain partitioned into 3 contiguous segments by work type.
    unsigned v = ((unsigned)blockIdx.x * SWIZZLE_PRIME) % G_TOTAL;

    if (v < G_GMM) {
        // ---- GMM latent rate: 8 elements/thread (2 float4 halves). --------
        // All 20 loads issued before any compute -> ~20 KB in flight/wave.
        v4f y4[2];
        v4f f[2][9];
        #pragma unroll
        for (int h = 0; h < 2; ++h) {
            int gid = v * 512 + h * 256 + threadIdx.x;   // float4 index
            int bc  = gid / (HW / 4);
            int hw4 = gid - bc * (HW / 4);
            const v4f* pp = (const v4f*)params + (size_t)bc * (9 * HW / 4) + hw4;
            y4[h] = ((const v4f*)y_hat)[gid];
            #pragma unroll
            for (int s = 0; s < 9; ++s)
                f[h][s] = pp[s * (HW / 4)];
        }
        float r = 0.0f;
        #pragma unroll
        for (int h = 0; h < 2; ++h)
            #pragma unroll
            for (int c = 0; c < 4; ++c)
                r += gmm_rate(y4[h][c], f[h][0][c], f[h][1][c], f[h][2][c],
                              f[h][3][c], f[h][4][c], f[h][5][c],
                              f[h][6][c], f[h][7][c], f[h][8][c]);
        block_write_partial(&partial[v], r);
    } else if (v < G_GMM + G_MSE) {
        // ---- MSE: contiguous 4096-float4 chunk per block, 8 loads/iter ----
        // x/x_hat are read-once streams: nontemporal, keep LLC for params.
        int mb = v - G_GMM;
        const v4f* x4  = (const v4f*)x;
        const v4f* xh4 = (const v4f*)xh;
        size_t base = (size_t)mb * 4096 + threadIdx.x;
        float a0 = 0.f, a1 = 0.f, a2 = 0.f, a3 = 0.f;
        #pragma unroll
        for (int it = 0; it < 4; ++it) {
            size_t b0 = base + (size_t)it * 1024;
            v4f p0 = __builtin_nontemporal_load(x4  + b0);
            v4f p1 = __builtin_nontemporal_load(x4  + b0 + 256);
            v4f p2 = __builtin_nontemporal_load(x4  + b0 + 512);
            v4f p3 = __builtin_nontemporal_load(x4  + b0 + 768);
            v4f q0 = __builtin_nontemporal_load(xh4 + b0);
            v4f q1 = __builtin_nontemporal_load(xh4 + b0 + 256);
            v4f q2 = __builtin_nontemporal_load(xh4 + b0 + 512);
            v4f q3 = __builtin_nontemporal_load(xh4 + b0 + 768);
            v4f d0 = q0 - p0, d1 = q1 - p1, d2 = q2 - p2, d3 = q3 - p3;
            a0 += d0.x*d0.x + d0.y*d0.y + d0.z*d0.z + d0.w*d0.w;
            a1 += d1.x*d1.x + d1.y*d1.y + d1.z*d1.z + d1.w*d1.w;
            a2 += d2.x*d2.x + d2.y*d2.y + d2.z*d2.z + d2.w*d2.w;
            a3 += d3.x*d3.x + d3.y*d3.y + d3.z*d3.z + d3.w*d3.w;
        }
        block_write_partial(&partial[v], (a0 + a1) + (a2 + a3));
    } else {
        // ---- Hyperlatent rate: 8 elements/thread --------------------------
        int hb = v - G_GMM - G_MSE;
        int g  = hb * 512 + threadIdx.x;
        v4f z0 = ((const v4f*)z_hat)[g];
        v4f z1 = ((const v4f*)z_hat)[g + 256];
        float r = 0.0f;
        #pragma unroll
        for (int j = 0; j < 8; ++j) {
            float z = (j < 4) ? z0[j] : z1[j - 4];
            float d = erf_fast((z + 0.5f) * INV_SQRT2)
                    - erf_fast((z - 0.5f) * INV_SQRT2);
            r += 1.0f - __log2f(fmaxf(d, 2e-6f));
        }
        block_write_partial(&partial[v], r);
    }
}

// Reduce partial segments: [0,G_GMM)=rate_y, [G_GMM,+G_MSE)=sq_err,
// [G_GMM+G_MSE,G_TOTAL)=rate_z.
__global__ void __launch_bounds__(256)
finalize_kernel(const double* __restrict__ partial, float* __restrict__ out) {
    __shared__ double sm[256];
    double seg[3];
    const int lo[3] = {0, G_GMM, G_GMM + G_MSE};
    const int hi[3] = {G_GMM, G_GMM + G_MSE, G_TOTAL};
    for (int k = 0; k < 3; ++k) {
        double a = 0.0;
        for (int i = lo[k] + threadIdx.x; i < hi[k]; i += 256) a += partial[i];
        sm[threadIdx.x] = a;
        __syncthreads();
        for (int off = 128; off > 0; off >>= 1) {
            if (threadIdx.x < (unsigned)off) sm[threadIdx.x] += sm[threadIdx.x + off];
            __syncthreads();
        }
        seg[k] = sm[0];
        __syncthreads();
    }
    if (threadIdx.x == 0) {
        double rate_y     = seg[0];
        double sq_err     = seg[1];
        double rate_z     = seg[2];
        double distortion = sq_err / (double)N_X;
        double bpp = (rate_y / (double)BB + rate_z / (double)BB) / (double)NUM_PIXELS;
        double loss = 0.01 * 255.0 * 255.0 * distortion + bpp;
        out[0] = (float)loss;
        out[1] = (float)distortion;
        out[2] = (float)bpp;
    }
}

extern "C" void kernel_launch(void* const* d_in, const int* in_sizes, int n_in,
                              void* d_out, int out_size, void* d_ws, size_t ws_size,
                              hipStream_t stream) {
    const float* x      = (const float*)d_in[0];
    const float* x_hat  = (const float*)d_in[1];
    const float* params = (const float*)d_in[2];
    const float* y_hat  = (const float*)d_in[3];
    const float* z_hat  = (const float*)d_in[4];
    float* out = (float*)d_out;
    double* partial = (double*)d_ws;   // G_TOTAL doubles, all written each call

    fused_kernel<<<G_TOTAL, 256, 0, stream>>>(x, x_hat, params, y_hat, z_hat, partial);
    finalize_kernel<<<1, 256, 0, stream>>>(partial, out);
}